// Round 10
// baseline (39364.566 us; speedup 1.0000x reference)
//
#include <hip/hip_runtime.h>
#include <hip/hip_bf16.h>

// Problem constants (match reference)
#define Tn 2048
#define Bn 32
#define Dn 256
#define Un 256
#define NBLK 8

using short8 = __attribute__((ext_vector_type(8))) short;
using f32x4  = __attribute__((ext_vector_type(4))) float;
using int4v  = __attribute__((ext_vector_type(4))) int;
using u16x2  = __attribute__((ext_vector_type(2))) unsigned short;

__device__ __forceinline__ unsigned short f2bf(float f) {
    unsigned int u = __builtin_bit_cast(unsigned int, f);
    u += 0x7fffu + ((u >> 16) & 1u);   // round-to-nearest-even
    return (unsigned short)(u >> 16);
}
__device__ __forceinline__ float bf2f(unsigned short v) {
    unsigned int u = ((unsigned int)v) << 16;
    return __builtin_bit_cast(float, u);
}
__device__ __forceinline__ float rcp_f(float x) { return __builtin_amdgcn_rcpf(x); }
__device__ __forceinline__ float sigm(float x)   { return rcp_f(1.0f + __expf(-x)); }
__device__ __forceinline__ float tanh_f(float x) { return 1.0f - 2.0f * rcp_f(__expf(2.0f * x) + 1.0f); }

// ---------------------------------------------------------------------------
// Kernel 1: zx = data @ Wx, stored bf16, layout [T][B][1024]. (Verbatim from
// the passing rounds 1-5; not the bottleneck.)
// ---------------------------------------------------------------------------
__global__ __launch_bounds__(512) void gemm_zx(const float* __restrict__ data,
                                               const float* __restrict__ Wx,
                                               unsigned short* __restrict__ zws)
{
    __shared__ unsigned short BsubT[128 * 40];

    const int bid = blockIdx.x;
    const int bn = bid & 7;
    const int bm = bid >> 3;
    const int tid = threadIdx.x;
    const int lane = tid & 63, wid = tid >> 6;
    const int wm = wid >> 2, wn = wid & 3;
    const int l15 = lane & 15, lk = lane >> 4;

    f32x4 acc[4][2];
    #pragma unroll
    for (int mt = 0; mt < 4; ++mt)
        #pragma unroll
        for (int nt = 0; nt < 2; ++nt)
            acc[mt][nt] = f32x4{0.f, 0.f, 0.f, 0.f};

    const int colStage = tid & 127;
    const int kqStage  = tid >> 7;

    for (int ks = 0; ks < 8; ++ks) {
        __syncthreads();
        {
            const float* wp = Wx + (size_t)(ks * 32 + kqStage) * 1024 + bn * 128 + colStage;
            #pragma unroll
            for (int kk = 0; kk < 8; ++kk) {
                float v = wp[(size_t)kk * 4 * 1024];
                BsubT[colStage * 40 + (kqStage + kk * 4)] = f2bf(v);
            }
        }
        __syncthreads();

        short8 afr[4];
        #pragma unroll
        for (int mt = 0; mt < 4; ++mt) {
            int row = bm * 128 + wm * 64 + mt * 16 + l15;
            const float* ap = data + (size_t)row * 256 + ks * 32 + lk * 8;
            float4 a0 = *(const float4*)(ap);
            float4 a1 = *(const float4*)(ap + 4);
            short8 a;
            a[0] = (short)f2bf(a0.x); a[1] = (short)f2bf(a0.y);
            a[2] = (short)f2bf(a0.z); a[3] = (short)f2bf(a0.w);
            a[4] = (short)f2bf(a1.x); a[5] = (short)f2bf(a1.y);
            a[6] = (short)f2bf(a1.z); a[7] = (short)f2bf(a1.w);
            afr[mt] = a;
        }
        #pragma unroll
        for (int nt = 0; nt < 2; ++nt) {
            int colL = wn * 32 + nt * 16 + l15;
            short8 bfr = *(const short8*)&BsubT[colL * 40 + lk * 8];
            #pragma unroll
            for (int mt = 0; mt < 4; ++mt)
                acc[mt][nt] = __builtin_amdgcn_mfma_f32_16x16x32_bf16(afr[mt], bfr, acc[mt][nt], 0, 0, 0);
        }
    }

    #pragma unroll
    for (int mt = 0; mt < 4; ++mt) {
        #pragma unroll
        for (int nt = 0; nt < 2; ++nt) {
            int col = bn * 128 + wn * 32 + nt * 16 + l15;
            #pragma unroll
            for (int r = 0; r < 4; ++r) {
                int row = bm * 128 + wm * 64 + mt * 16 + lk * 4 + r;
                int b_ = row >> 11;
                int t_ = row & 2047;
                zws[(size_t)(t_ * 32 + b_) * 1024 + col] = f2bf(acc[mt][nt][r]);
            }
        }
    }
}

// ---------------------------------------------------------------------------
// Kernel 1b: WhT[col][k] = bf16(Wh[k][col]) — one-time transpose.
// ---------------------------------------------------------------------------
__global__ void wh_transpose(const float* __restrict__ Wh,
                             unsigned short* __restrict__ WhT)
{
    const int c = blockIdx.x;
    const int k = threadIdx.x;
    WhT[c * 256 + k] = f2bf(Wh[(size_t)k * 1024 + c]);
}

// ---------------------------------------------------------------------------
// asm helpers (literal offsets). NOTE: no counted vmcnt anywhere — every wait
// is vmcnt(0), so compiler spills/reloads cannot corrupt the accounting.
// ---------------------------------------------------------------------------
#define SC_LOADX4(d, base, OFF) \
    asm volatile("global_load_dwordx4 %0, %1, off offset:" OFF " sc0 sc1" \
                 : "=v"(d) : "v"(base) : "memory")
#define H_STORE(base, val, OFF) \
    asm volatile("global_store_dword %0, %1, off offset:" OFF " sc0 sc1" \
                 :: "v"(base), "v"(val) : "memory")
#define WAIT0 asm volatile("s_waitcnt vmcnt(0)" ::: "memory")

// repack tagged dwords -> bf16 A-fragment, 4 MFMAs (KS must be a literal)
#define MFMA_SLICE(KS) do {                                                          \
    int4v p_;                                                                        \
    p_[0] = (int)((((unsigned)tg[2*(KS)][1]) << 16)     | ((unsigned)tg[2*(KS)][0]     & 0xffffu)); \
    p_[1] = (int)((((unsigned)tg[2*(KS)][3]) << 16)     | ((unsigned)tg[2*(KS)][2]     & 0xffffu)); \
    p_[2] = (int)((((unsigned)tg[2*(KS)+1][1]) << 16)   | ((unsigned)tg[2*(KS)+1][0]   & 0xffffu)); \
    p_[3] = (int)((((unsigned)tg[2*(KS)+1][3]) << 16)   | ((unsigned)tg[2*(KS)+1][2]   & 0xffffu)); \
    short8 af_ = __builtin_bit_cast(short8, p_);                                     \
    acc[0] = __builtin_amdgcn_mfma_f32_16x16x32_bf16(af_, Bf[0][KS], acc[0], 0,0,0); \
    acc[1] = __builtin_amdgcn_mfma_f32_16x16x32_bf16(af_, Bf[1][KS], acc[1], 0,0,0); \
    acc[2] = __builtin_amdgcn_mfma_f32_16x16x32_bf16(af_, Bf[2][KS], acc[2], 0,0,0); \
    acc[3] = __builtin_amdgcn_mfma_f32_16x16x32_bf16(af_, Bf[3][KS], acc[3], 0,0,0); \
} while (0)

#define ISSUE_BULK(bb) do {                                       \
    SC_LOADX4(tg[0],  bb, "0");   SC_LOADX4(tg[1],  bb, "16");    \
    SC_LOADX4(tg[2],  bb, "128"); SC_LOADX4(tg[3],  bb, "144");   \
    SC_LOADX4(tg[4],  bb, "256"); SC_LOADX4(tg[5],  bb, "272");   \
    SC_LOADX4(tg[6],  bb, "384"); SC_LOADX4(tg[7],  bb, "400");   \
    SC_LOADX4(tg[8],  bb, "512"); SC_LOADX4(tg[9],  bb, "528");   \
    SC_LOADX4(tg[10], bb, "640"); SC_LOADX4(tg[11], bb, "656");   \
    SC_LOADX4(tg[12], bb, "768"); SC_LOADX4(tg[13], bb, "784");   \
    SC_LOADX4(tg[14], bb, "896"); SC_LOADX4(tg[15], bb, "912");   \
} while (0)

#define TAG_SUM(s) do {                                           \
    s = u16x2{0, 0};                                              \
    _Pragma("unroll")                                             \
    for (int i_ = 0; i_ < 16; ++i_)                               \
        _Pragma("unroll")                                         \
        for (int j_ = 0; j_ < 4; ++j_)                            \
            s += __builtin_bit_cast(u16x2, tg[i_][j_]);           \
} while (0)

struct ZxRegs { unsigned int v[4][4]; };   // [gate][r], low 16 bits = bf16

// ---------------------------------------------------------------------------
// Kernel 2: recurrence. Tagged-dword LLC exchange (R5's proven protocol) with
// a three-tier read path: (1) optimistic bulk + full tag-sum verify (the only
// correctness gate), (2) on miss, skinny 4-dword sentinel spin (128B/wave per
// round — avoids R5's 512KB/round congestion), (3) re-bulk + R5 verify loop.
// 8 blocks x 256 thr (4 waves = 2m x 2n); Wh gate-cols in registers; h
// published as ((t+1)<<16)|bf16(h) dwords, fire-and-forget. No flags, no
// barriers, no counted vmcnt. zx prefetch + out stores are plain compiler
// ops placed after the publish; their latency hides under the next poll.
// ---------------------------------------------------------------------------
__global__ __launch_bounds__(256, 1) void lstm_rec(
    const unsigned short* __restrict__ WhT,   // [1024][256] bf16
    const float* __restrict__ bias,           // [1024]
    const unsigned short* __restrict__ zws,   // [T][32][1024] bf16
    unsigned int* __restrict__ hT,            // [2][32][256] tagged dwords (memset 0)
    float* __restrict__ out)                  // [32][T][256] f32
{
    const int chunk = blockIdx.x;             // 0..7
    const int tid  = threadIdx.x;
    const int lane = tid & 63;
    const int wid  = tid >> 6;                // 0..3
    const int wm   = wid >> 1;                // batch half (m)
    const int wn   = wid & 1;                 // u half (n)
    const int l15  = lane & 15, lk = lane >> 4;

    const int u   = chunk * 32 + wn * 16 + l15;
    const int row = wm * 16 + l15;            // this lane's batch row (A-fragment)

    // ---- Wh fragments into registers: Bf[g][ks], col = g*256+u (128 VGPR)
    short8 Bf[4][8];
    #pragma unroll
    for (int g = 0; g < 4; ++g)
        #pragma unroll
        for (int ks = 0; ks < 8; ++ks)
            Bf[g][ks] = *(const short8*)(WhT + (size_t)(g * 256 + u) * 256 + ks * 32 + lk * 8);

    float bias_r[4];
    #pragma unroll
    for (int g = 0; g < 4; ++g) bias_r[g] = bias[g * 256 + u];

    float c_state[4];
    #pragma unroll
    for (int r = 0; r < 4; ++r) c_state[r] = 0.0f;

    // ---- exchange bases (parity 0 / 1)
    const unsigned int* hb0 = hT + (size_t)row * 256;
    const unsigned int* hb1 = hb0 + Bn * Un;
    const unsigned long long bb0 = (unsigned long long)(hb0 + lk * 8);   // bulk base
    const unsigned long long bb1 = (unsigned long long)(hb1 + lk * 8);
    const unsigned long long sb0 = (unsigned long long)(hb0 + lk * 32);  // sentinel base
    const unsigned long long sb1 = (unsigned long long)(hb1 + lk * 32);
    unsigned int* hwb0p = hT + (size_t)(wm * 16 + lk * 4) * 256 + u;     // h write base
    const unsigned long long hwb0 = (unsigned long long)hwb0p;
    const unsigned long long hwb1 = (unsigned long long)(hwb0p + Bn * Un);

    // zx(t) single buffer; refilled after each publish (WAR dependency keeps order)
    ZxRegs zx;
    #pragma unroll
    for (int g = 0; g < 4; ++g)
        #pragma unroll
        for (int r = 0; r < 4; ++r)
            zx.v[g][r] = zws[(size_t)(wm * 16 + lk * 4 + r) * 1024 + g * 256 + u];

    // ---- gates + tagged publish + out stores + zx refill for t+1
    auto publish = [&](int t, const f32x4* acc) {
        const unsigned int tagw = ((unsigned int)(t + 1)) << 16;
        const unsigned long long hwb = (t & 1) ? hwb1 : hwb0;
        float hv[4];
        #pragma unroll
        for (int r = 0; r < 4; ++r) {
            const float zi = acc[0][r] + bf2f((unsigned short)zx.v[0][r]) + bias_r[0];
            const float zf = acc[1][r] + bf2f((unsigned short)zx.v[1][r]) + bias_r[1];
            const float zg = acc[2][r] + bf2f((unsigned short)zx.v[2][r]) + bias_r[2];
            const float zo = acc[3][r] + bf2f((unsigned short)zx.v[3][r]) + bias_r[3];
            const float ig = sigm(zi), fg = sigm(zf);
            const float gg = tanh_f(zg), og = sigm(zo);
            const float cs = fg * c_state[r] + ig * gg;
            c_state[r] = cs;
            const float h = og * tanh_f(cs);
            const unsigned int dw = tagw | (unsigned int)f2bf(h);
            if (r == 0) H_STORE(hwb, dw, "0");
            if (r == 1) H_STORE(hwb, dw, "1024");
            if (r == 2) H_STORE(hwb, dw, "2048");
            if (r == 3) H_STORE(hwb, dw, "3072");
            hv[r] = h;
        }
        // out stores (plain, fire-and-forget; cached path)
        #pragma unroll
        for (int r = 0; r < 4; ++r)
            out[(size_t)(wm * 16 + lk * 4 + r) * (Tn * Un) + (size_t)t * Un + u] = hv[r];
        // zx refill for t+1 (plain loads; land under next poll's vmcnt(0))
        if (t + 1 < Tn) {
            #pragma unroll
            for (int g = 0; g < 4; ++g)
                #pragma unroll
                for (int r = 0; r < 4; ++r)
                    zx.v[g][r] = zws[((size_t)(t + 1) * 32 + wm * 16 + lk * 4 + r) * 1024
                                     + g * 256 + u];
        }
    };

    // ---- step t >= 1: three-tier read of h(t-1), then MFMA + publish
    auto step = [&](int t, unsigned long long bb, unsigned long long sb) {
        const unsigned int tt = (unsigned int)t;
        const unsigned short t64 = (unsigned short)(64u * tt);
        int4v tg[16];

        // tier 1: optimistic bulk + full verify
        ISSUE_BULK(bb);
        WAIT0;
        __builtin_amdgcn_sched_barrier(0);   // rule #18
        u16x2 s;
        TAG_SUM(s);
        if (!__all((int)(s[1] == t64))) {
            // tier 2: skinny sentinel spin (liveness only; 4 dwords/lane/round)
            unsigned int s0, s1, s2, s3;
            bool ok;
            do {
                asm volatile(
                    "global_load_dword %0, %4, off sc0 sc1\n\t"
                    "global_load_dword %1, %4, off offset:64 sc0 sc1\n\t"
                    "global_load_dword %2, %4, off offset:512 sc0 sc1\n\t"
                    "global_load_dword %3, %4, off offset:576 sc0 sc1\n\t"
                    "s_waitcnt vmcnt(0)"
                    : "=&v"(s0), "=&v"(s1), "=&v"(s2), "=&v"(s3)
                    : "v"(sb) : "memory");
                ok = ((s0 >> 16) == tt) & ((s1 >> 16) == tt) &
                     ((s2 >> 16) == tt) & ((s3 >> 16) == tt);
            } while (!__all((int)ok));
            // tier 3: re-bulk + verify loop (R5's proven correctness gate)
            do {
                ISSUE_BULK(bb);
                WAIT0;
                __builtin_amdgcn_sched_barrier(0);
                TAG_SUM(s);
            } while (!__all((int)(s[1] == t64)));
        }
        __builtin_amdgcn_sched_barrier(0);

        // MFMA: 4 independent 8-deep chains, only after full verify
        f32x4 acc[4];
        #pragma unroll
        for (int g = 0; g < 4; ++g) acc[g] = f32x4{0.f, 0.f, 0.f, 0.f};
        MFMA_SLICE(0); MFMA_SLICE(1); MFMA_SLICE(2); MFMA_SLICE(3);
        MFMA_SLICE(4); MFMA_SLICE(5); MFMA_SLICE(6); MFMA_SLICE(7);

        publish(t, acc);
    };

    // ---- t = 0: h(-1)=0 -> acc=0
    {
        f32x4 acc0[4];
        #pragma unroll
        for (int g = 0; g < 4; ++g) acc0[g] = f32x4{0.f, 0.f, 0.f, 0.f};
        publish(0, acc0);
    }

    // ---- main loop: odd t reads parity0, even t reads parity1.
    for (int t = 1; t + 1 < Tn; t += 2) {
        step(t,     bb0, sb0);
        step(t + 1, bb1, sb1);
    }
    step(Tn - 1, bb0, sb0);   // t = 2047 (odd)
}

// ---------------------------------------------------------------------------
extern "C" void kernel_launch(void* const* d_in, const int* in_sizes, int n_in,
                              void* d_out, int out_size, void* d_ws, size_t ws_size,
                              hipStream_t stream)
{
    const float* data = (const float*)d_in[0];   // [32,2048,256]
    const float* Wx   = (const float*)d_in[1];   // [256,1024]
    const float* Wh   = (const float*)d_in[2];   // [256,1024]
    const float* bias = (const float*)d_in[3];   // [1024]
    float* out = (float*)d_out;

    char* ws = (char*)d_ws;
    unsigned short* zws = (unsigned short*)ws;                 // 128 MB: [T][B][1024] bf16
    size_t off = (size_t)Tn * Bn * 1024 * 2;
    unsigned short* WhT = (unsigned short*)(ws + off);         // 512 KB
    off += (size_t)1024 * 256 * 2;
    unsigned int* hT = (unsigned int*)(ws + off);              // 64 KB: [2][32][256] tagged

    // tags must start at 0 (uniqueness argument) — every launch.
    hipMemsetAsync(hT, 0, (size_t)2 * Bn * Un * sizeof(unsigned int), stream);

    wh_transpose<<<dim3(1024), dim3(256), 0, stream>>>(Wh, WhT);
    gemm_zx<<<dim3(4096), dim3(512), 0, stream>>>(data, Wx, zws);
    lstm_rec<<<dim3(NBLK), dim3(256), 0, stream>>>(WhT, bias, zws, hT, out);
}

// Round 11
// 10305.019 us; speedup vs baseline: 3.8199x; 3.8199x over previous
//
#include <hip/hip_runtime.h>
#include <hip/hip_bf16.h>

// Problem constants (match reference)
#define Tn 2048
#define Bn 32
#define Dn 256
#define Un 256
#define NBLK 8

using short8 = __attribute__((ext_vector_type(8))) short;
using f32x4  = __attribute__((ext_vector_type(4))) float;
using int4v  = __attribute__((ext_vector_type(4))) int;
using u16x2  = __attribute__((ext_vector_type(2))) unsigned short;

__device__ __forceinline__ unsigned short f2bf(float f) {
    unsigned int u = __builtin_bit_cast(unsigned int, f);
    u += 0x7fffu + ((u >> 16) & 1u);   // round-to-nearest-even
    return (unsigned short)(u >> 16);
}
__device__ __forceinline__ float bf2f(unsigned short v) {
    unsigned int u = ((unsigned int)v) << 16;
    return __builtin_bit_cast(float, u);
}
__device__ __forceinline__ float rcp_f(float x) { return __builtin_amdgcn_rcpf(x); }
__device__ __forceinline__ float sigm(float x)   { return rcp_f(1.0f + __expf(-x)); }
__device__ __forceinline__ float tanh_f(float x) { return 1.0f - 2.0f * rcp_f(__expf(2.0f * x) + 1.0f); }

// ---------------------------------------------------------------------------
// Kernel 1: zx = data @ Wx, stored bf16, layout [T][B][1024]. (Verbatim from
// the passing rounds; not the bottleneck.)
// ---------------------------------------------------------------------------
__global__ __launch_bounds__(512) void gemm_zx(const float* __restrict__ data,
                                               const float* __restrict__ Wx,
                                               unsigned short* __restrict__ zws)
{
    __shared__ unsigned short BsubT[128 * 40];

    const int bid = blockIdx.x;
    const int bn = bid & 7;
    const int bm = bid >> 3;
    const int tid = threadIdx.x;
    const int lane = tid & 63, wid = tid >> 6;
    const int wm = wid >> 2, wn = wid & 3;
    const int l15 = lane & 15, lk = lane >> 4;

    f32x4 acc[4][2];
    #pragma unroll
    for (int mt = 0; mt < 4; ++mt)
        #pragma unroll
        for (int nt = 0; nt < 2; ++nt)
            acc[mt][nt] = f32x4{0.f, 0.f, 0.f, 0.f};

    const int colStage = tid & 127;
    const int kqStage  = tid >> 7;

    for (int ks = 0; ks < 8; ++ks) {
        __syncthreads();
        {
            const float* wp = Wx + (size_t)(ks * 32 + kqStage) * 1024 + bn * 128 + colStage;
            #pragma unroll
            for (int kk = 0; kk < 8; ++kk) {
                float v = wp[(size_t)kk * 4 * 1024];
                BsubT[colStage * 40 + (kqStage + kk * 4)] = f2bf(v);
            }
        }
        __syncthreads();

        short8 afr[4];
        #pragma unroll
        for (int mt = 0; mt < 4; ++mt) {
            int row = bm * 128 + wm * 64 + mt * 16 + l15;
            const float* ap = data + (size_t)row * 256 + ks * 32 + lk * 8;
            float4 a0 = *(const float4*)(ap);
            float4 a1 = *(const float4*)(ap + 4);
            short8 a;
            a[0] = (short)f2bf(a0.x); a[1] = (short)f2bf(a0.y);
            a[2] = (short)f2bf(a0.z); a[3] = (short)f2bf(a0.w);
            a[4] = (short)f2bf(a1.x); a[5] = (short)f2bf(a1.y);
            a[6] = (short)f2bf(a1.z); a[7] = (short)f2bf(a1.w);
            afr[mt] = a;
        }
        #pragma unroll
        for (int nt = 0; nt < 2; ++nt) {
            int colL = wn * 32 + nt * 16 + l15;
            short8 bfr = *(const short8*)&BsubT[colL * 40 + lk * 8];
            #pragma unroll
            for (int mt = 0; mt < 4; ++mt)
                acc[mt][nt] = __builtin_amdgcn_mfma_f32_16x16x32_bf16(afr[mt], bfr, acc[mt][nt], 0, 0, 0);
        }
    }

    #pragma unroll
    for (int mt = 0; mt < 4; ++mt) {
        #pragma unroll
        for (int nt = 0; nt < 2; ++nt) {
            int col = bn * 128 + wn * 32 + nt * 16 + l15;
            #pragma unroll
            for (int r = 0; r < 4; ++r) {
                int row = bm * 128 + wm * 64 + mt * 16 + lk * 4 + r;
                int b_ = row >> 11;
                int t_ = row & 2047;
                zws[(size_t)(t_ * 32 + b_) * 1024 + col] = f2bf(acc[mt][nt][r]);
            }
        }
    }
}

// ---------------------------------------------------------------------------
// Kernel 1b: WhT[col][k] = bf16(Wh[k][col]) — one-time transpose.
// ---------------------------------------------------------------------------
__global__ void wh_transpose(const float* __restrict__ Wh,
                             unsigned short* __restrict__ WhT)
{
    const int c = blockIdx.x;
    const int k = threadIdx.x;
    WhT[c * 256 + k] = f2bf(Wh[(size_t)k * 1024 + c]);
}

// ---------------------------------------------------------------------------
// asm helpers (literal offsets). No counted vmcnt anywhere — every wait is
// vmcnt(0), so compiler-inserted vmem cannot corrupt the accounting.
// ---------------------------------------------------------------------------
#define SC_LOADX4(d, base, OFF) \
    asm volatile("global_load_dwordx4 %0, %1, off offset:" OFF " sc0 sc1" \
                 : "=v"(d) : "v"(base) : "memory")
#define H_STORE(base, val, OFF) \
    asm volatile("global_store_dword %0, %1, off offset:" OFF " sc0 sc1" \
                 :: "v"(base), "v"(val) : "memory")
#define WAIT0 asm volatile("s_waitcnt vmcnt(0)" ::: "memory")

// repack tagged dwords -> bf16 A-fragment, 4 MFMAs (KS must be a literal)
#define MFMA_SLICE(KS) do {                                                          \
    int4v p_;                                                                        \
    p_[0] = (int)((((unsigned)tg[2*(KS)][1]) << 16)     | ((unsigned)tg[2*(KS)][0]     & 0xffffu)); \
    p_[1] = (int)((((unsigned)tg[2*(KS)][3]) << 16)     | ((unsigned)tg[2*(KS)][2]     & 0xffffu)); \
    p_[2] = (int)((((unsigned)tg[2*(KS)+1][1]) << 16)   | ((unsigned)tg[2*(KS)+1][0]   & 0xffffu)); \
    p_[3] = (int)((((unsigned)tg[2*(KS)+1][3]) << 16)   | ((unsigned)tg[2*(KS)+1][2]   & 0xffffu)); \
    short8 af_ = __builtin_bit_cast(short8, p_);                                     \
    acc[0] = __builtin_amdgcn_mfma_f32_16x16x32_bf16(af_, Bf[0][KS], acc[0], 0,0,0); \
    acc[1] = __builtin_amdgcn_mfma_f32_16x16x32_bf16(af_, Bf[1][KS], acc[1], 0,0,0); \
    acc[2] = __builtin_amdgcn_mfma_f32_16x16x32_bf16(af_, Bf[2][KS], acc[2], 0,0,0); \
    acc[3] = __builtin_amdgcn_mfma_f32_16x16x32_bf16(af_, Bf[3][KS], acc[3], 0,0,0); \
} while (0)

#define ISSUE_BULK(bb) do {                                       \
    SC_LOADX4(tg[0],  bb, "0");   SC_LOADX4(tg[1],  bb, "16");    \
    SC_LOADX4(tg[2],  bb, "128"); SC_LOADX4(tg[3],  bb, "144");   \
    SC_LOADX4(tg[4],  bb, "256"); SC_LOADX4(tg[5],  bb, "272");   \
    SC_LOADX4(tg[6],  bb, "384"); SC_LOADX4(tg[7],  bb, "400");   \
    SC_LOADX4(tg[8],  bb, "512"); SC_LOADX4(tg[9],  bb, "528");   \
    SC_LOADX4(tg[10], bb, "640"); SC_LOADX4(tg[11], bb, "656");   \
    SC_LOADX4(tg[12], bb, "768"); SC_LOADX4(tg[13], bb, "784");   \
    SC_LOADX4(tg[14], bb, "896"); SC_LOADX4(tg[15], bb, "912");   \
} while (0)

#define TAG_SUM(s) do {                                           \
    s = u16x2{0, 0};                                              \
    _Pragma("unroll")                                             \
    for (int i_ = 0; i_ < 16; ++i_)                               \
        _Pragma("unroll")                                         \
        for (int j_ = 0; j_ < 4; ++j_)                            \
            s += __builtin_bit_cast(u16x2, tg[i_][j_]);           \
} while (0)

// gates + tagged publish + out stores. Uses surrounding scope: acc, zx-capture
// CUR_, bias_r, c_state, wm, lk, u, out, hwb0/hwb1. No lambda (rule: loop
// state must stay in registers; lambdas risk outlining -> scratch, R10 bug).
#define GATES_PUBLISH(T_, CUR_) do {                                             \
    const unsigned int tagw_ = ((unsigned int)((T_) + 1)) << 16;                 \
    const unsigned long long hwb_ = ((T_) & 1) ? hwb1 : hwb0;                    \
    float hv_[4];                                                                \
    _Pragma("unroll")                                                            \
    for (int r = 0; r < 4; ++r) {                                                \
        const float zi = acc[0][r] + bf2f((unsigned short)(CUR_).v[0][r]) + bias_r[0]; \
        const float zf = acc[1][r] + bf2f((unsigned short)(CUR_).v[1][r]) + bias_r[1]; \
        const float zg = acc[2][r] + bf2f((unsigned short)(CUR_).v[2][r]) + bias_r[2]; \
        const float zo = acc[3][r] + bf2f((unsigned short)(CUR_).v[3][r]) + bias_r[3]; \
        const float ig = sigm(zi), fg = sigm(zf);                                \
        const float gg = tanh_f(zg), og = sigm(zo);                              \
        const float cs = fg * c_state[r] + ig * gg;                              \
        c_state[r] = cs;                                                         \
        const float h_ = og * tanh_f(cs);                                        \
        const unsigned int dw_ = tagw_ | (unsigned int)f2bf(h_);                 \
        if (r == 0) H_STORE(hwb_, dw_, "0");                                     \
        if (r == 1) H_STORE(hwb_, dw_, "1024");                                  \
        if (r == 2) H_STORE(hwb_, dw_, "2048");                                  \
        if (r == 3) H_STORE(hwb_, dw_, "3072");                                  \
        hv_[r] = h_;                                                             \
    }                                                                            \
    _Pragma("unroll")                                                            \
    for (int r = 0; r < 4; ++r)                                                  \
        out[(size_t)(wm * 16 + lk * 4 + r) * (Tn * Un) + (size_t)(T_) * Un + u] = hv_[r]; \
} while (0)

#define ZX_REFILL(T_) do {                                                       \
    if ((T_) < Tn) {                                                             \
        _Pragma("unroll")                                                        \
        for (int g_ = 0; g_ < 4; ++g_)                                           \
            _Pragma("unroll")                                                    \
            for (int r_ = 0; r_ < 4; ++r_)                                       \
                zx.v[g_][r_] = zws[((size_t)(T_) * 32 + wm * 16 + lk * 4 + r_) * 1024 \
                                   + g_ * 256 + u];                              \
    }                                                                            \
} while (0)

struct ZxRegs { unsigned int v[4][4]; };   // [gate][r], low 16 bits = bf16

// ---------------------------------------------------------------------------
// Kernel 2: recurrence. Tagged-dword LLC exchange with three-tier read:
// (1) optimistic bulk + full tag-sum verify (the only correctness gate),
// (2) on miss, skinny 4-dword sentinel spin (128B/wave/round),
// (3) re-bulk + verify loop (R5's proven gate).
// 8 blocks x 256 thr (4 waves = 2m x 2n); Wh gate-cols in registers; h
// published as ((t+1)<<16)|bf16(h) dwords, fire-and-forget. No flags, no
// barriers, no lambdas (R10: outlined lambdas spilled Bf to scratch, VGPR 68,
// 35ms). Single t-loop; parity bases via uniform ternaries; zx single-buffer
// with explicit capture, refilled right after verify so the loads fly under
// MFMA/gates/next-poll.
// ---------------------------------------------------------------------------
__global__ __launch_bounds__(256, 1) void lstm_rec(
    const unsigned short* __restrict__ WhT,   // [1024][256] bf16
    const float* __restrict__ bias,           // [1024]
    const unsigned short* __restrict__ zws,   // [T][32][1024] bf16
    unsigned int* __restrict__ hT,            // [2][32][256] tagged dwords (memset 0)
    float* __restrict__ out)                  // [32][T][256] f32
{
    const int chunk = blockIdx.x;             // 0..7
    const int tid  = threadIdx.x;
    const int lane = tid & 63;
    const int wid  = tid >> 6;                // 0..3
    const int wm   = wid >> 1;                // batch half (m)
    const int wn   = wid & 1;                 // u half (n)
    const int l15  = lane & 15, lk = lane >> 4;

    const int u   = chunk * 32 + wn * 16 + l15;
    const int row = wm * 16 + l15;            // this lane's batch row (A-fragment)

    // ---- Wh fragments into registers: Bf[g][ks], col = g*256+u (64 VGPR)
    short8 Bf[4][8];
    #pragma unroll
    for (int g = 0; g < 4; ++g)
        #pragma unroll
        for (int ks = 0; ks < 8; ++ks)
            Bf[g][ks] = *(const short8*)(WhT + (size_t)(g * 256 + u) * 256 + ks * 32 + lk * 8);

    float bias_r[4];
    #pragma unroll
    for (int g = 0; g < 4; ++g) bias_r[g] = bias[g * 256 + u];

    float c_state[4];
    #pragma unroll
    for (int r = 0; r < 4; ++r) c_state[r] = 0.0f;

    // ---- exchange bases (parity 0 / 1)
    const unsigned int* hb0 = hT + (size_t)row * 256;
    const unsigned int* hb1 = hb0 + Bn * Un;
    const unsigned long long bb0 = (unsigned long long)(hb0 + lk * 8);   // bulk base
    const unsigned long long bb1 = (unsigned long long)(hb1 + lk * 8);
    const unsigned long long sb0 = (unsigned long long)(hb0 + lk * 32);  // sentinel base
    const unsigned long long sb1 = (unsigned long long)(hb1 + lk * 32);
    unsigned int* hwb0p = hT + (size_t)(wm * 16 + lk * 4) * 256 + u;     // h write base
    const unsigned long long hwb0 = (unsigned long long)hwb0p;
    const unsigned long long hwb1 = (unsigned long long)(hwb0p + Bn * Un);

    // zx(t=0)
    ZxRegs zx;
    #pragma unroll
    for (int g = 0; g < 4; ++g)
        #pragma unroll
        for (int r = 0; r < 4; ++r)
            zx.v[g][r] = zws[(size_t)(wm * 16 + lk * 4 + r) * 1024 + g * 256 + u];

    // ---- t = 0: h(-1)=0 -> acc=0; capture zx, refill for t=1, publish.
    {
        f32x4 acc[4];
        #pragma unroll
        for (int g = 0; g < 4; ++g) acc[g] = f32x4{0.f, 0.f, 0.f, 0.f};
        ZxRegs cur = zx;
        ZX_REFILL(1);
        GATES_PUBLISH(0, cur);
    }

    // ---- main loop
    for (int t = 1; t < Tn; ++t) {
        const unsigned long long bb = (t & 1) ? bb0 : bb1;   // read parity (t-1)&1
        const unsigned long long sb = (t & 1) ? sb0 : sb1;
        const unsigned int tt = (unsigned int)t;
        const unsigned short t64 = (unsigned short)(64u * tt);

        int4v tg[16];

        // tier 1: optimistic bulk + full verify
        ISSUE_BULK(bb);
        WAIT0;
        __builtin_amdgcn_sched_barrier(0);   // rule #18
        u16x2 s;
        TAG_SUM(s);
        if (!__all((int)(s[1] == t64))) {
            // tier 2: skinny sentinel spin (liveness only)
            unsigned int s0, s1, s2, s3;
            bool ok;
            do {
                asm volatile(
                    "global_load_dword %0, %4, off sc0 sc1\n\t"
                    "global_load_dword %1, %4, off offset:64 sc0 sc1\n\t"
                    "global_load_dword %2, %4, off offset:512 sc0 sc1\n\t"
                    "global_load_dword %3, %4, off offset:576 sc0 sc1\n\t"
                    "s_waitcnt vmcnt(0)"
                    : "=&v"(s0), "=&v"(s1), "=&v"(s2), "=&v"(s3)
                    : "v"(sb) : "memory");
                ok = ((s0 >> 16) == tt) & ((s1 >> 16) == tt) &
                     ((s2 >> 16) == tt) & ((s3 >> 16) == tt);
            } while (!__all((int)ok));
            // tier 3: re-bulk + verify loop (proven correctness gate)
            do {
                ISSUE_BULK(bb);
                WAIT0;
                __builtin_amdgcn_sched_barrier(0);
                TAG_SUM(s);
            } while (!__all((int)(s[1] == t64)));
        }
        __builtin_amdgcn_sched_barrier(0);

        // capture zx(t); issue zx(t+1) refill — flies under MFMA/gates/next poll
        ZxRegs cur = zx;
        ZX_REFILL(t + 1);

        // MFMA: 4 independent 8-deep chains, only after full verify
        f32x4 acc[4];
        #pragma unroll
        for (int g = 0; g < 4; ++g) acc[g] = f32x4{0.f, 0.f, 0.f, 0.f};
        MFMA_SLICE(0); MFMA_SLICE(1); MFMA_SLICE(2); MFMA_SLICE(3);
        MFMA_SLICE(4); MFMA_SLICE(5); MFMA_SLICE(6); MFMA_SLICE(7);

        GATES_PUBLISH(t, cur);
    }
}

// ---------------------------------------------------------------------------
extern "C" void kernel_launch(void* const* d_in, const int* in_sizes, int n_in,
                              void* d_out, int out_size, void* d_ws, size_t ws_size,
                              hipStream_t stream)
{
    const float* data = (const float*)d_in[0];   // [32,2048,256]
    const float* Wx   = (const float*)d_in[1];   // [256,1024]
    const float* Wh   = (const float*)d_in[2];   // [256,1024]
    const float* bias = (const float*)d_in[3];   // [1024]
    float* out = (float*)d_out;

    char* ws = (char*)d_ws;
    unsigned short* zws = (unsigned short*)ws;                 // 128 MB: [T][B][1024] bf16
    size_t off = (size_t)Tn * Bn * 1024 * 2;
    unsigned short* WhT = (unsigned short*)(ws + off);         // 512 KB
    off += (size_t)1024 * 256 * 2;
    unsigned int* hT = (unsigned int*)(ws + off);              // 64 KB: [2][32][256] tagged

    // tags must start at 0 (uniqueness argument) — every launch.
    hipMemsetAsync(hT, 0, (size_t)2 * Bn * Un * sizeof(unsigned int), stream);

    wh_transpose<<<dim3(1024), dim3(256), 0, stream>>>(Wh, WhT);
    gemm_zx<<<dim3(4096), dim3(512), 0, stream>>>(data, Wx, zws);
    lstm_rec<<<dim3(NBLK), dim3(256), 0, stream>>>(WhT, bias, zws, hT, out);
}